// Round 1
// baseline (177.297 us; speedup 1.0000x reference)
//
#include <hip/hip_runtime.h>
#include <hip/hip_bf16.h>

// GraphSAGE 2-layer: N=50000, D=128, DEG=16.
// Pipeline: convert(x->bf16, W->bf16 transposed) ; [gather-concat ; mfma GEMM] x2
typedef __attribute__((ext_vector_type(8))) short short8;
typedef __attribute__((ext_vector_type(4))) float f32x4;

#define N_NODES 50000
#define D 128
#define DEG 16
#define K2 256   // 2*D
#define BM 64    // rows per GEMM block

static __device__ __forceinline__ unsigned short f2b(float f) {
    union { float f; unsigned int u; } v; v.f = f;
    // round-to-nearest-even bf16
    return (unsigned short)((v.u + 0x7fffu + ((v.u >> 16) & 1u)) >> 16);
}
static __device__ __forceinline__ float b2f(unsigned short u) {
    union { unsigned int u; float f; } v; v.u = ((unsigned int)u) << 16;
    return v.f;
}

// ---- x (f32, N*D) -> bf16 ----
__global__ void convert_x(const float* __restrict__ x, unsigned short* __restrict__ xb, int n_elems) {
    int i = (blockIdx.x * blockDim.x + threadIdx.x) * 4;
    int stride = gridDim.x * blockDim.x * 4;
    for (int e = i; e < n_elems; e += stride) {
        float4 v = *(const float4*)(x + e);
        ushort4 o;
        o.x = f2b(v.x); o.y = f2b(v.y); o.z = f2b(v.z); o.w = f2b(v.w);
        *(ushort4*)(xb + e) = o;
    }
}

// ---- W (K2 x D, row-major k,n f32) -> Wt (D x K2, row-major n,k bf16), both layers ----
__global__ void convert_w(const float* __restrict__ W1, const float* __restrict__ W2,
                          unsigned short* __restrict__ Wt1, unsigned short* __restrict__ Wt2) {
    int i = blockIdx.x * blockDim.x + threadIdx.x;
    if (i >= K2 * D) return;
    int k = i / D, n = i % D;          // coalesced read over n
    Wt1[n * K2 + k] = f2b(W1[i]);
    Wt2[n * K2 + k] = f2b(W2[i]);
}

// ---- gather + concat: hcat[i] = [feat[i], mean_j feat[nbr[i][j]]] (bf16) ----
__global__ void gather_concat(const unsigned short* __restrict__ feat,  // N x D bf16
                              const int* __restrict__ nbr,              // N x DEG
                              unsigned short* __restrict__ hcat)        // N x K2 bf16
{
    int gid  = blockIdx.x * blockDim.x + threadIdx.x;
    int wave = gid >> 6;
    int lane = threadIdx.x & 63;
    int nwaves = (gridDim.x * blockDim.x) >> 6;
    for (int row = wave; row < N_NODES; row += nwaves) {
        const int4* np = (const int4*)(nbr + row * DEG);
        int4 n0 = np[0], n1 = np[1], n2 = np[2], n3 = np[3];
        int idx[DEG] = { n0.x, n0.y, n0.z, n0.w, n1.x, n1.y, n1.z, n1.w,
                         n2.x, n2.y, n2.z, n2.w, n3.x, n3.y, n3.z, n3.w };
        // each lane covers 2 dims via one b32 load (64 lanes x 4B = 256B/row)
        unsigned int self = *(const unsigned int*)(feat + row * D + lane * 2);
        float ax = 0.f, ay = 0.f;
        #pragma unroll
        for (int j = 0; j < DEG; ++j) {
            unsigned int p = *(const unsigned int*)(feat + idx[j] * D + lane * 2);
            ax += b2f((unsigned short)(p & 0xffffu));
            ay += b2f((unsigned short)(p >> 16));
        }
        *(unsigned int*)(hcat + row * K2 + lane * 2) = self;
        unsigned int m = ((unsigned int)f2b(ay * 0.0625f) << 16) | (unsigned int)f2b(ax * 0.0625f);
        *(unsigned int*)(hcat + row * K2 + D + lane * 2) = m;
    }
}

// ---- GEMM: out = relu(hcat @ W + b); A 64xK2 staged in LDS, B frags in regs ----
template <int OUT_BF16>
__global__ __launch_bounds__(256)
void gemm_sage(const unsigned short* __restrict__ hcat,  // N x K2 bf16
               const unsigned short* __restrict__ wt,    // D x K2 bf16 (n-major)
               const float* __restrict__ bias,           // D f32
               void* __restrict__ out)
{
    __shared__ __align__(16) unsigned short Hl[BM * 264];  // row stride 264 (pad 8)
    const int tid  = threadIdx.x;
    const int row0 = blockIdx.x * BM;
    const int lane = tid & 63;
    const int w    = tid >> 6;     // wave 0..3 -> 32-col strip
    const int quad = lane >> 4;
    const int l16  = lane & 15;
    const int n_base = w * 32;

    // B fragments: B[k][n], n = n_base + ct*16 + l16, k = kk*32 + quad*8 + j
    short8 bfrag[8][2];
    #pragma unroll
    for (int kk = 0; kk < 8; ++kk)
        #pragma unroll
        for (int ct = 0; ct < 2; ++ct) {
            int n = n_base + ct * 16 + l16;
            int k = kk * 32 + quad * 8;
            bfrag[kk][ct] = *(const short8*)(wt + n * K2 + k);
        }

    // Stage A tile: 64 rows x 256 cols bf16 = 2048 16B-chunks, 8 per thread
    #pragma unroll
    for (int i = 0; i < 8; ++i) {
        int c   = tid + i * 256;
        int r   = c >> 5;              // 32 chunks per row
        int off = (c & 31) * 8;
        int srow = row0 + r;
        if (srow >= N_NODES) srow = N_NODES - 1;   // clamp; guarded at store
        *(short8*)(&Hl[r * 264 + off]) = *(const short8*)(hcat + srow * K2 + off);
    }
    __syncthreads();

    f32x4 acc[4][2];
    #pragma unroll
    for (int rt = 0; rt < 4; ++rt)
        #pragma unroll
        for (int ct = 0; ct < 2; ++ct)
            acc[rt][ct] = (f32x4){0.f, 0.f, 0.f, 0.f};

    #pragma unroll
    for (int kk = 0; kk < 8; ++kk) {
        short8 afrag[4];
        #pragma unroll
        for (int rt = 0; rt < 4; ++rt)
            afrag[rt] = *(const short8*)(&Hl[(rt * 16 + l16) * 264 + kk * 32 + quad * 8]);
        #pragma unroll
        for (int rt = 0; rt < 4; ++rt)
            #pragma unroll
            for (int ct = 0; ct < 2; ++ct)
                acc[rt][ct] = __builtin_amdgcn_mfma_f32_16x16x32_bf16(
                    afrag[rt], bfrag[kk][ct], acc[rt][ct], 0, 0, 0);
    }

    // Epilogue: C[row = row0 + rt*16 + quad*4 + r][col = n_base + ct*16 + l16]
    float bv0 = bias[n_base + l16];
    float bv1 = bias[n_base + 16 + l16];
    #pragma unroll
    for (int rt = 0; rt < 4; ++rt) {
        int grow_base = row0 + rt * 16 + quad * 4;
        #pragma unroll
        for (int r = 0; r < 4; ++r) {
            int grow = grow_base + r;
            if (grow >= N_NODES) continue;
            #pragma unroll
            for (int ct = 0; ct < 2; ++ct) {
                float v = acc[rt][ct][r] + (ct ? bv1 : bv0);
                v = v > 0.f ? v : 0.f;
                int col = n_base + ct * 16 + l16;
                if (OUT_BF16)
                    ((unsigned short*)out)[grow * D + col] = f2b(v);
                else
                    ((float*)out)[grow * D + col] = v;
            }
        }
    }
}

extern "C" void kernel_launch(void* const* d_in, const int* in_sizes, int n_in,
                              void* d_out, int out_size, void* d_ws, size_t ws_size,
                              hipStream_t stream) {
    const float* x  = (const float*)d_in[0];
    const int*   nb = (const int*)d_in[1];
    const float* W1 = (const float*)d_in[2];
    const float* b1 = (const float*)d_in[3];
    const float* W2 = (const float*)d_in[4];
    const float* b2 = (const float*)d_in[5];

    char* ws = (char*)d_ws;
    unsigned short* Wt1  = (unsigned short*)(ws);
    unsigned short* Wt2  = (unsigned short*)(ws + 65536);
    unsigned short* xb   = (unsigned short*)(ws + 131072);              // reused as h1 (bf16)
    unsigned short* hcat = (unsigned short*)(ws + 131072 + 12800000);   // N x 256 bf16

    convert_x<<<6250, 256, 0, stream>>>(x, xb, N_NODES * D);
    convert_w<<<128, 256, 0, stream>>>(W1, W2, Wt1, Wt2);

    const int ggrid = 2048;                       // 8192 waves, ~6 rows each
    const int mgrid = (N_NODES + BM - 1) / BM;    // 782

    // layer 1
    gather_concat<<<ggrid, 256, 0, stream>>>(xb, nb, hcat);
    gemm_sage<1><<<mgrid, 256, 0, stream>>>(hcat, Wt1, b1, xb);   // h1 (bf16) overlays xb
    // layer 2
    gather_concat<<<ggrid, 256, 0, stream>>>(xb, nb, hcat);
    gemm_sage<0><<<mgrid, 256, 0, stream>>>(hcat, Wt2, b2, d_out);
}